// Round 4
// baseline (273.110 us; speedup 1.0000x reference)
//
#include <hip/hip_runtime.h>
#include <hip/hip_bf16.h>

// Attention block: x[2,2048,1024] @ w_qkv^T -> split heads (H=16, Hd=64) ->
// causal softmax attention -> @ w_out^T.
// Device dtypes: inputs FLOAT32, output FLOAT32 (reference is all-f32 jax).
// Internally bf16 MFMA with f32 accumulation (bf16-floor threshold expects it).
// Pipeline: cvt f32->bf16 (x, w_qkv, w_out) -> gemm_nt<1> (QKV proj, scatter
// to [B,H,L,64] bf16) -> attn_fwd (flash, online softmax, swapped QK^T) ->
// gemm_nt<0> (out proj -> d_out as f32).

typedef __bf16 bf16;
typedef __bf16 bf16x8 __attribute__((ext_vector_type(8)));
typedef __bf16 bf16x4 __attribute__((ext_vector_type(4)));
typedef float  f32x4  __attribute__((ext_vector_type(4)));

#define MFMA16(a, b, c) __builtin_amdgcn_mfma_f32_16x16x32_bf16(a, b, c, 0, 0, 0)

__global__ __launch_bounds__(256) void cvt_f32_bf16(
    const float* __restrict__ src, bf16* __restrict__ dst, int n4) {
  int i = blockIdx.x * blockDim.x + threadIdx.x;
  if (i < n4) {
    float4 v = ((const float4*)src)[i];
    bf16x4 o;
    o[0] = (bf16)v.x; o[1] = (bf16)v.y; o[2] = (bf16)v.z; o[3] = (bf16)v.w;
    ((bf16x4*)dst)[i] = o;
  }
}

__device__ __forceinline__ void gload_lds16(const bf16* g, bf16* l) {
  __builtin_amdgcn_global_load_lds(
      (const __attribute__((address_space(1))) void*)g,
      (__attribute__((address_space(3))) void*)l, 16, 0, 0);
}

// Stage a ROWS x 64 bf16 tile (row stride `ld` elems in global) into LDS.
// LDS layout is linear [ROWS][64] but each row's eight 16B slots are permuted
// by slot ^= (row&7)  (applied on the GLOBAL source side, since
// global_load_lds writes linearly: base + lane*16). Read back with read_swz.
template <int ROWS>
__device__ __forceinline__ void stage_tile(const bf16* __restrict__ src, int ld,
                                           bf16* lds, int tid) {
  const int wid = tid >> 6;
#pragma unroll
  for (int i = 0; i < ROWS / 32; ++i) {
    int c = i * 256 + tid;              // 16B chunk index
    int row = c >> 3;
    int slot = (c & 7) ^ (row & 7);     // pre-swizzled source slot
    gload_lds16(src + row * ld + slot * 8, lds + i * 2048 + wid * 512);
  }
}

// Read 8 contiguous bf16 of tile[row][kbyte/2 ..] with the XOR un-swizzle.
__device__ __forceinline__ bf16x8 read_swz(const bf16* lds, int row, int kbyte) {
  int byte = row * 128 + (kbyte ^ ((row & 7) << 4));
  return *(const bf16x8*)((const char*)lds + byte);
}

// C[m,n] = sum_k A[m,k] * Bt[n,k].  128x128 tile, BK=64, 4 waves in 2x2,
// each wave 64x64 (4x4 fragments of 16x16), mfma_f32_16x16x32_bf16.
// MODE 0: Cf row-major [M,N] FLOAT32.  MODE 1: QKV scatter into C0/C1/C2
// as [B=2,H=16,L=2048,64] bf16.
template <int MODE>
__global__ __launch_bounds__(256) void gemm_nt(
    const bf16* __restrict__ A, const bf16* __restrict__ Bt,
    bf16* __restrict__ C0, bf16* __restrict__ C1, bf16* __restrict__ C2,
    float* __restrict__ Cf,
    int M, int N, int K, int nbm) {
  __shared__ bf16 ldsA[128 * 64];
  __shared__ bf16 ldsB[128 * 64];
  const int tid = threadIdx.x;
  const int lane = tid & 63, wid = tid >> 6;
  const int wr = wid >> 1, wc = wid & 1;
  const int bm = blockIdx.x % nbm, bn = blockIdx.x / nbm;
  const int l15 = lane & 15, g = lane >> 4;

  f32x4 acc[4][4] = {};
  const bf16* Ab = A + (size_t)bm * 128 * K;
  const bf16* Bb = Bt + (size_t)bn * 128 * K;

  for (int k0 = 0; k0 < K; k0 += 64) {
    __syncthreads();  // protect LDS from previous iteration's readers
    stage_tile<128>(Ab + k0, K, ldsA, tid);
    stage_tile<128>(Bb + k0, K, ldsB, tid);
    __syncthreads();  // drains vmcnt (compiler emits full waitcnt before barrier)
#pragma unroll
    for (int kc = 0; kc < 2; ++kc) {
      bf16x8 af[4], bfr[4];
#pragma unroll
      for (int mi = 0; mi < 4; ++mi)
        af[mi] = read_swz(ldsA, wr * 64 + mi * 16 + l15, kc * 64 + g * 16);
#pragma unroll
      for (int ni = 0; ni < 4; ++ni)
        bfr[ni] = read_swz(ldsB, wc * 64 + ni * 16 + l15, kc * 64 + g * 16);
#pragma unroll
      for (int mi = 0; mi < 4; ++mi)
#pragma unroll
        for (int ni = 0; ni < 4; ++ni)
          acc[mi][ni] = MFMA16(af[mi], bfr[ni], acc[mi][ni]);
    }
  }

  const int mbase = bm * 128 + wr * 64, nbase = bn * 128 + wc * 64;
#pragma unroll
  for (int mi = 0; mi < 4; ++mi) {
#pragma unroll
    for (int ni = 0; ni < 4; ++ni) {
#pragma unroll
      for (int r = 0; r < 4; ++r) {
        // D layout (m89-verified): col = lane&15, row = (lane>>4)*4 + r
        int m = mbase + mi * 16 + g * 4 + r;
        int n = nbase + ni * 16 + l15;
        if (MODE == 0) {
          Cf[(size_t)m * N + n] = acc[mi][ni][r];   // f32 output
        } else {
          bf16 v = (bf16)acc[mi][ni][r];
          int part = n >> 10;               // 0:Q 1:K 2:V
          int hh = (n >> 6) & 15, hd = n & 63;
          int bb = m >> 11, ll = m & 2047;
          bf16* dst = (part == 0) ? C0 : ((part == 1) ? C1 : C2);
          dst[(((size_t)(bb * 16 + hh)) * 2048 + ll) * 64 + hd] = v;
        }
      }
    }
  }
}

// Causal flash attention. Q/K/V: [B*H, L=2048, 64] bf16.  O2: [B*L, 1024] bf16
// (head dim h*64+d within row, so the out-proj is a plain NT GEMM).
// Block: 256 threads = 4 waves; each wave owns 16 q-rows of a 64-row q-tile.
// Swapped QK^T: S^T = mfma(K_frag, Q_frag) so lane (q = lane&15) holds P
// values for its own q-row -> softmax is per-lane + shfl_xor(16,32).
__global__ __launch_bounds__(256) void attn_fwd(
    const bf16* __restrict__ Q, const bf16* __restrict__ Kb,
    const bf16* __restrict__ Vb, bf16* __restrict__ O2) {
  __shared__ bf16 ldsK[64 * 64];       // swizzled-staged K tile [64 kv][64 d]
  __shared__ bf16 ldsVt[64 * 72];      // V^T tile [64 d][64 kv], +8 pad
  __shared__ bf16 ldsP[4][16 * 72];    // per-wave P [16 q][64 kv], +8 pad

  const int tid = threadIdx.x, lane = tid & 63, wid = tid >> 6;
  const int l15 = lane & 15, g = lane >> 4;
  const int qt = blockIdx.x & 31;      // L/64 = 32 q-tiles
  const int bh = blockIdx.x >> 5;      // 0..31
  const int b = bh >> 4, h = bh & 15;
  const bf16* Qh = Q + (size_t)bh * 2048 * 64;
  const bf16* Kh = Kb + (size_t)bh * 2048 * 64;
  const bf16* Vh = Vb + (size_t)bh * 2048 * 64;
  const int q0 = qt * 64;
  const int qw = q0 + wid * 16;        // this wave's q rows: qw..qw+15
  const int qrow = qw + l15;           // this lane's q row

  // Q fragment (B operand): lane holds Q[qrow][dk*32 + g*8 + j], direct global.
  bf16x8 qf[2];
#pragma unroll
  for (int dk = 0; dk < 2; ++dk)
    qf[dk] = *(const bf16x8*)(Qh + (size_t)qrow * 64 + dk * 32 + g * 8);

  float m_run = -__builtin_inff(), l_run = 0.f;
  f32x4 oacc[4] = {};  // O^T[d = dsub*16 + g*4 + r][q = l15]

  const int ntiles = qt + 1;
  for (int t = 0; t < ntiles; ++t) {
    const int kv0 = t * 64;
    __syncthreads();
    stage_tile<64>(Kh + (size_t)kv0 * 64, 64, ldsK, tid);
    // V^T staging (register transpose; scalar LDS writes, small volume)
#pragma unroll
    for (int i = 0; i < 2; ++i) {
      int c = i * 256 + tid;
      int r = c >> 3, c0 = (c & 7) * 8;
      bf16x8 v = *(const bf16x8*)(Vh + (size_t)(kv0 + r) * 64 + c0);
#pragma unroll
      for (int j = 0; j < 8; ++j) ldsVt[(c0 + j) * 72 + r] = v[j];
    }
    __syncthreads();

    // S^T tiles: A = K[16kv,32d], B = Q -> D[kvloc = g*4+r][q = l15]
    f32x4 s[4] = {};
#pragma unroll
    for (int sub = 0; sub < 4; ++sub) {
#pragma unroll
      for (int dk = 0; dk < 2; ++dk) {
        bf16x8 kf = read_swz(ldsK, sub * 16 + l15, dk * 64 + g * 16);
        s[sub] = MFMA16(kf, qf[dk], s[sub]);
      }
    }

    // online softmax over this tile's 64 kv (16 values per lane)
    float pvv[16];
    float mtile = -__builtin_inff();
#pragma unroll
    for (int sub = 0; sub < 4; ++sub)
#pragma unroll
      for (int r = 0; r < 4; ++r) {
        int kv = kv0 + sub * 16 + g * 4 + r;
        float v = s[sub][r] * 0.125f;          // scale = Hd^-0.5
        if (kv > qrow) v = -__builtin_inff();  // causal mask
        pvv[sub * 4 + r] = v;
        mtile = fmaxf(mtile, v);
      }
    mtile = fmaxf(mtile, __shfl_xor(mtile, 16));
    mtile = fmaxf(mtile, __shfl_xor(mtile, 32));
    float mnew = fmaxf(m_run, mtile);          // finite: kv0 <= qw always
    float alpha = __expf(m_run - mnew);        // first tile: exp(-inf) = 0
    float lsum = 0.f;
#pragma unroll
    for (int sub = 0; sub < 4; ++sub) {
      bf16x4 pb;
#pragma unroll
      for (int r = 0; r < 4; ++r) {
        float e = __expf(pvv[sub * 4 + r] - mnew);
        lsum += e;
        pb[r] = (bf16)e;
      }
      *(bf16x4*)(&ldsP[wid][l15 * 72 + sub * 16 + g * 4]) = pb;
    }
    lsum += __shfl_xor(lsum, 16);
    lsum += __shfl_xor(lsum, 32);
    l_run = alpha * l_run + lsum;
    m_run = mnew;
#pragma unroll
    for (int dsub = 0; dsub < 4; ++dsub) {
      oacc[dsub][0] *= alpha; oacc[dsub][1] *= alpha;
      oacc[dsub][2] *= alpha; oacc[dsub][3] *= alpha;
    }
    // PV: O^T += V^T * P^T  (A = V^T frag, B = P^T frag; both read as
    // row = lane&15, 8 contiguous k at g*8 from padded LDS)
#pragma unroll
    for (int kc = 0; kc < 2; ++kc) {
      bf16x8 pf = *(const bf16x8*)(&ldsP[wid][l15 * 72 + kc * 32 + g * 8]);
#pragma unroll
      for (int dsub = 0; dsub < 4; ++dsub) {
        bf16x8 vt = *(const bf16x8*)(&ldsVt[(dsub * 16 + l15) * 72 + kc * 32 + g * 8]);
        oacc[dsub] = MFMA16(vt, pf, oacc[dsub]);
      }
    }
  }

  const float linv = 1.f / l_run;
#pragma unroll
  for (int dsub = 0; dsub < 4; ++dsub)
#pragma unroll
    for (int r = 0; r < 4; ++r) {
      int d = dsub * 16 + g * 4 + r;
      O2[((size_t)(b * 2048 + qrow)) * 1024 + h * 64 + d] =
          (bf16)(oacc[dsub][r] * linv);
    }
}

extern "C" void kernel_launch(void* const* d_in, const int* in_sizes, int n_in,
                              void* d_out, int out_size, void* d_ws, size_t ws_size,
                              hipStream_t stream) {
  const float* x     = (const float*)d_in[0];   // [2,2048,1024] f32
  // d_in[1] = causal mask: known tril, not read
  const float* w_qkv = (const float*)d_in[2];   // [3072,1024] f32
  const float* w_out = (const float*)d_in[3];   // [1024,1024] f32
  float* out = (float*)d_out;                   // [2,2048,1024] f32

  char* ws = (char*)d_ws;
  bf16* xb    = (bf16*)(ws);                        // [4096,1024]   8 MiB
  bf16* wqkvb = (bf16*)(ws + ((size_t)8 << 20));    // [3072,1024]   6 MiB
  bf16* woutb = (bf16*)(ws + ((size_t)14 << 20));   // [1024,1024]   2 MiB
  bf16* Qb    = (bf16*)(ws + ((size_t)16 << 20));   // [2,16,2048,64] 8 MiB
  bf16* Kbuf  = (bf16*)(ws + ((size_t)24 << 20));   // 8 MiB
  bf16* Vbuf  = (bf16*)(ws + ((size_t)32 << 20));   // 8 MiB
  bf16* O2    = (bf16*)(ws + ((size_t)40 << 20));   // [4096,1024]   8 MiB

  // f32 -> bf16 conversions
  cvt_f32_bf16<<<dim3(4096), 256, 0, stream>>>(x, xb, 4096 * 1024 / 4);
  cvt_f32_bf16<<<dim3(3072), 256, 0, stream>>>(w_qkv, wqkvb, 3072 * 1024 / 4);
  cvt_f32_bf16<<<dim3(1024), 256, 0, stream>>>(w_out, woutb, 1024 * 1024 / 4);

  // QKV projection: M=4096, N=3072, K=1024
  gemm_nt<1><<<dim3(32 * 24), 256, 0, stream>>>(xb, wqkvb, Qb, Kbuf, Vbuf,
                                                nullptr, 4096, 3072, 1024, 32);
  // Flash attention: 32 q-tiles x 32 (b,h)
  attn_fwd<<<dim3(32 * 32), 256, 0, stream>>>(Qb, Kbuf, Vbuf, O2);
  // Output projection: M=4096, N=1024, K=1024 -> f32 out
  gemm_nt<0><<<dim3(32 * 8), 256, 0, stream>>>(O2, woutb, nullptr, nullptr,
                                               nullptr, out, 4096, 1024, 1024, 32);
}

// Round 6
// 205.654 us; speedup vs baseline: 1.3280x; 1.3280x over previous
//
#include <hip/hip_runtime.h>
#include <hip/hip_bf16.h>

// Attention block: x[2,2048,1024] @ w_qkv^T -> split heads (H=16, Hd=64) ->
// causal softmax attention -> @ w_out^T.
// Device dtypes: inputs FLOAT32, output FLOAT32. Internally bf16 MFMA + f32 acc.
// Pipeline: cvt_all (f32->bf16, fused) -> gemm_nt<1> (QKV proj; Q,K to
// [bh,L,64], V TRANSPOSED to [bh,64,L]) -> attn_fwd (flash, double-buffered
// K/Vt staging, peeled causal diagonal) -> gemm_nt<0> (out proj -> f32 d_out).

typedef __bf16 bf16;
typedef __bf16 bf16x8 __attribute__((ext_vector_type(8)));
typedef __bf16 bf16x4 __attribute__((ext_vector_type(4)));
typedef float  f32x4  __attribute__((ext_vector_type(4)));

#define MFMA16(a, b, c) __builtin_amdgcn_mfma_f32_16x16x32_bf16(a, b, c, 0, 0, 0)

// Fused f32->bf16 convert. Destinations are contiguous in d_ws:
// xb (1048576 float4) | wqkvb (786432) | woutb (262144).
__global__ __launch_bounds__(256) void cvt_all(
    const float* __restrict__ x, const float* __restrict__ wq,
    const float* __restrict__ wo, bf16* __restrict__ dst) {
  int i = blockIdx.x * 256 + threadIdx.x;  // float4 index, grid covers exactly
  const float* src;
  int off;
  if (i < 1048576) {
    src = x; off = i;
  } else if (i < 1048576 + 786432) {
    src = wq; off = i - 1048576;
  } else {
    src = wo; off = i - (1048576 + 786432);
  }
  float4 v = ((const float4*)src)[off];
  bf16x4 o;
  o[0] = (bf16)v.x; o[1] = (bf16)v.y; o[2] = (bf16)v.z; o[3] = (bf16)v.w;
  ((bf16x4*)dst)[i] = o;
}

__device__ __forceinline__ void gload_lds16(const bf16* g, bf16* l) {
  __builtin_amdgcn_global_load_lds(
      (const __attribute__((address_space(1))) void*)g,
      (__attribute__((address_space(3))) void*)l, 16, 0, 0);
}

// Stage a ROWS x 64 bf16 tile (row stride `ld` elems in global) into LDS.
// LDS layout is linear [ROWS][64] but each row's eight 16B slots are permuted
// by slot ^= (row&7)  (applied on the GLOBAL source side, since
// global_load_lds writes linearly: base + lane*16). Read back with read_swz.
template <int ROWS>
__device__ __forceinline__ void stage_tile(const bf16* __restrict__ src, int ld,
                                           bf16* lds, int tid) {
  const int wid = tid >> 6;
#pragma unroll
  for (int i = 0; i < ROWS / 32; ++i) {
    int c = i * 256 + tid;              // 16B chunk index
    int row = c >> 3;
    int slot = (c & 7) ^ (row & 7);     // pre-swizzled source slot
    gload_lds16(src + row * ld + slot * 8, lds + i * 2048 + wid * 512);
  }
}

// Read 8 contiguous bf16 of tile[row][kbyte/2 ..] with the XOR un-swizzle.
__device__ __forceinline__ bf16x8 read_swz(const bf16* lds, int row, int kbyte) {
  int byte = row * 128 + (kbyte ^ ((row & 7) << 4));
  return *(const bf16x8*)((const char*)lds + byte);
}

// C[m,n] = sum_k A[m,k] * Bt[n,k].  128x128 tile, BK=64, 4 waves in 2x2,
// each wave 64x64 (4x4 fragments of 16x16), mfma_f32_16x16x32_bf16.
// MODE 0: Cf row-major [M,N] FLOAT32.
// MODE 1: QKV scatter: Q,K -> C0/C1 [bh,2048,64] bf16; V -> C2 TRANSPOSED
//         [bh,64,2048] bf16 (so attention stages V^T directly).
template <int MODE>
__global__ __launch_bounds__(256) void gemm_nt(
    const bf16* __restrict__ A, const bf16* __restrict__ Bt,
    bf16* __restrict__ C0, bf16* __restrict__ C1, bf16* __restrict__ C2,
    float* __restrict__ Cf,
    int M, int N, int K, int nbm) {
  __shared__ bf16 ldsA[128 * 64];
  __shared__ bf16 ldsB[128 * 64];
  const int tid = threadIdx.x;
  const int lane = tid & 63, wid = tid >> 6;
  const int wr = wid >> 1, wc = wid & 1;
  const int bm = blockIdx.x % nbm, bn = blockIdx.x / nbm;
  const int l15 = lane & 15, g = lane >> 4;

  f32x4 acc[4][4] = {};
  const bf16* Ab = A + (size_t)bm * 128 * K;
  const bf16* Bb = Bt + (size_t)bn * 128 * K;

  for (int k0 = 0; k0 < K; k0 += 64) {
    __syncthreads();  // protect LDS from previous iteration's readers
    stage_tile<128>(Ab + k0, K, ldsA, tid);
    stage_tile<128>(Bb + k0, K, ldsB, tid);
    __syncthreads();  // drains vmcnt (compiler emits full waitcnt before barrier)
#pragma unroll
    for (int kc = 0; kc < 2; ++kc) {
      bf16x8 af[4], bfr[4];
#pragma unroll
      for (int mi = 0; mi < 4; ++mi)
        af[mi] = read_swz(ldsA, wr * 64 + mi * 16 + l15, kc * 64 + g * 16);
#pragma unroll
      for (int ni = 0; ni < 4; ++ni)
        bfr[ni] = read_swz(ldsB, wc * 64 + ni * 16 + l15, kc * 64 + g * 16);
#pragma unroll
      for (int mi = 0; mi < 4; ++mi)
#pragma unroll
        for (int ni = 0; ni < 4; ++ni)
          acc[mi][ni] = MFMA16(af[mi], bfr[ni], acc[mi][ni]);
    }
  }

  const int mbase = bm * 128 + wr * 64, nbase = bn * 128 + wc * 64;
#pragma unroll
  for (int mi = 0; mi < 4; ++mi) {
#pragma unroll
    for (int ni = 0; ni < 4; ++ni) {
#pragma unroll
      for (int r = 0; r < 4; ++r) {
        // D layout (m89-verified): col = lane&15, row = (lane>>4)*4 + r
        int m = mbase + mi * 16 + g * 4 + r;
        int n = nbase + ni * 16 + l15;
        if (MODE == 0) {
          Cf[(size_t)m * N + n] = acc[mi][ni][r];   // f32 output
        } else {
          bf16 v = (bf16)acc[mi][ni][r];
          int part = n >> 10;               // 0:Q 1:K 2:V
          int hh = (n >> 6) & 15, hd = n & 63;
          int bb = m >> 11, ll = m & 2047;
          size_t bhb = (size_t)(bb * 16 + hh);
          if (part == 2) {
            C2[(bhb * 64 + hd) * 2048 + ll] = v;          // V^T [bh][d][L]
          } else {
            bf16* dst = (part == 0) ? C0 : C1;
            dst[(bhb * 2048 + ll) * 64 + hd] = v;         // [bh][L][d]
          }
        }
      }
    }
  }
}

// Causal flash attention. Q/K: [bh, 2048, 64] bf16; Vt: [bh, 64, 2048] bf16.
// O2: [B*L, 1024] bf16 (head dim h*64+d within row -> out-proj is plain NT).
// Block: 256 threads = 4 waves; each wave owns 16 q-rows of a 64-row q-tile.
// Swapped QK^T: S^T = mfma(K_frag, Q_frag) so lane (q = lane&15) holds P
// values for its own q-row -> softmax is per-lane + shfl_xor(16,32).
// Double-buffered K/Vt staging (prefetch next tile before computing current);
// causal diagonal tile peeled (main loop needs no masking).
__global__ __launch_bounds__(256) void attn_fwd(
    const bf16* __restrict__ Q, const bf16* __restrict__ Kb,
    const bf16* __restrict__ Vt, bf16* __restrict__ O2) {
  __shared__ bf16 ldsK[2][64 * 64];    // swizzled K tiles [64 kv][64 d]
  __shared__ bf16 ldsVt[2][64 * 64];   // swizzled V^T tiles [64 d][64 kv]
  __shared__ bf16 ldsP[4][16 * 72];    // per-wave P [16 q][64 kv], +8 pad

  const int tid = threadIdx.x, lane = tid & 63, wid = tid >> 6;
  const int l15 = lane & 15, g = lane >> 4;
  const int qt = 31 - (blockIdx.x >> 5);  // longest blocks dispatched first
  const int bh = blockIdx.x & 31;
  const int b = bh >> 4, h = bh & 15;
  const bf16* Qh  = Q  + (size_t)bh * 2048 * 64;
  const bf16* Kh  = Kb + (size_t)bh * 2048 * 64;
  const bf16* VtH = Vt + (size_t)bh * 64 * 2048;
  const int q0 = qt * 64;
  const int qrow = q0 + wid * 16 + l15;  // this lane's q row

  // Q fragment (B operand): lane holds Q[qrow][dk*32 + g*8 + j], direct global.
  bf16x8 qf[2];
#pragma unroll
  for (int dk = 0; dk < 2; ++dk)
    qf[dk] = *(const bf16x8*)(Qh + (size_t)qrow * 64 + dk * 32 + g * 8);

  float m_run = -__builtin_inff(), l_run = 0.f;
  f32x4 oacc[4] = {};  // O^T[d = dsub*16 + g*4 + r][q = l15]

  // One K/V tile step. masked==true only for the diagonal tile (t == qt).
  auto step = [&](bool masked, int curb) {
    // S^T: A = K[16kv,32d], B = Q -> D[kvloc = g*4+r][q = l15]
    f32x4 s[4] = {};
#pragma unroll
    for (int sub = 0; sub < 4; ++sub) {
#pragma unroll
      for (int dk = 0; dk < 2; ++dk) {
        bf16x8 kf = read_swz(&ldsK[curb][0], sub * 16 + l15, dk * 64 + g * 16);
        s[sub] = MFMA16(kf, qf[dk], s[sub]);
      }
    }
    // online softmax over this tile's 64 kv (16 values per lane)
    float pvv[16];
    float mtile = -__builtin_inff();
#pragma unroll
    for (int sub = 0; sub < 4; ++sub)
#pragma unroll
      for (int r = 0; r < 4; ++r) {
        float v = s[sub][r] * 0.125f;          // scale = Hd^-0.5
        if (masked) {
          int kvl = sub * 16 + g * 4 + r;      // kv local to tile
          if (kvl > wid * 16 + l15) v = -__builtin_inff();  // causal
        }
        pvv[sub * 4 + r] = v;
        mtile = fmaxf(mtile, v);
      }
    mtile = fmaxf(mtile, __shfl_xor(mtile, 16));
    mtile = fmaxf(mtile, __shfl_xor(mtile, 32));
    float mnew = fmaxf(m_run, mtile);
    float alpha = __expf(m_run - mnew);        // first tile: exp(-inf) = 0
    float lsum = 0.f;
#pragma unroll
    for (int sub = 0; sub < 4; ++sub) {
      bf16x4 pb;
#pragma unroll
      for (int r = 0; r < 4; ++r) {
        float e = __expf(pvv[sub * 4 + r] - mnew);
        lsum += e;
        pb[r] = (bf16)e;
      }
      *(bf16x4*)(&ldsP[wid][l15 * 72 + sub * 16 + g * 4]) = pb;
    }
    lsum += __shfl_xor(lsum, 16);
    lsum += __shfl_xor(lsum, 32);
    l_run = alpha * l_run + lsum;
    m_run = mnew;
#pragma unroll
    for (int dsub = 0; dsub < 4; ++dsub) {
      oacc[dsub][0] *= alpha; oacc[dsub][1] *= alpha;
      oacc[dsub][2] *= alpha; oacc[dsub][3] *= alpha;
    }
    // PV: O^T += V^T * P^T  (A = Vt frag rows=d, B = P^T frag from LDS)
#pragma unroll
    for (int kc = 0; kc < 2; ++kc) {
      bf16x8 pf = *(const bf16x8*)(&ldsP[wid][l15 * 72 + kc * 32 + g * 8]);
#pragma unroll
      for (int dsub = 0; dsub < 4; ++dsub) {
        bf16x8 vf = read_swz(&ldsVt[curb][0], dsub * 16 + l15, kc * 64 + g * 16);
        oacc[dsub] = MFMA16(vf, pf, oacc[dsub]);
      }
    }
  };

  // prologue: stage tile 0
  stage_tile<64>(Kh, 64, &ldsK[0][0], tid);
  stage_tile<64>(VtH, 2048, &ldsVt[0][0], tid);
  __syncthreads();

  int cur = 0;
  for (int t = 0; t < qt; ++t) {       // unmasked steps (kv tile strictly below diag)
    // prefetch tile t+1 into the other buffer (in flight during compute)
    stage_tile<64>(Kh + (size_t)(t + 1) * 64 * 64, 64, &ldsK[cur ^ 1][0], tid);
    stage_tile<64>(VtH + (t + 1) * 64, 2048, &ldsVt[cur ^ 1][0], tid);
    step(false, cur);
    __syncthreads();                   // staging drained + all waves done reading
    cur ^= 1;
  }
  step(true, cur);                     // diagonal tile, causal-masked

  const float linv = 1.f / l_run;
#pragma unroll
  for (int dsub = 0; dsub < 4; ++dsub)
#pragma unroll
    for (int r = 0; r < 4; ++r) {
      int d = dsub * 16 + g * 4 + r;
      O2[((size_t)(b * 2048 + qrow)) * 1024 + h * 64 + d] =
          (bf16)(oacc[dsub][r] * linv);
    }
}

extern "C" void kernel_launch(void* const* d_in, const int* in_sizes, int n_in,
                              void* d_out, int out_size, void* d_ws, size_t ws_size,
                              hipStream_t stream) {
  const float* x     = (const float*)d_in[0];   // [2,2048,1024] f32
  // d_in[1] = causal mask: known tril, not read
  const float* w_qkv = (const float*)d_in[2];   // [3072,1024] f32
  const float* w_out = (const float*)d_in[3];   // [1024,1024] f32
  float* out = (float*)d_out;                   // [2,2048,1024] f32

  char* ws = (char*)d_ws;
  bf16* xb    = (bf16*)(ws);                        // [4096,1024]   8 MiB
  bf16* wqkvb = (bf16*)(ws + ((size_t)8 << 20));    // [3072,1024]   6 MiB
  bf16* woutb = (bf16*)(ws + ((size_t)14 << 20));   // [1024,1024]   2 MiB
  bf16* Qb    = (bf16*)(ws + ((size_t)16 << 20));   // [32,2048,64]  8 MiB
  bf16* Kbuf  = (bf16*)(ws + ((size_t)24 << 20));   // [32,2048,64]  8 MiB
  bf16* Vtb   = (bf16*)(ws + ((size_t)32 << 20));   // [32,64,2048]  8 MiB (V^T)
  bf16* O2    = (bf16*)(ws + ((size_t)40 << 20));   // [4096,1024]   8 MiB

  // fused f32 -> bf16 conversion (dst regions contiguous at ws base)
  cvt_all<<<dim3(8192), 256, 0, stream>>>(x, w_qkv, w_out, xb);

  // QKV projection: M=4096, N=3072, K=1024 (V stored transposed)
  gemm_nt<1><<<dim3(32 * 24), 256, 0, stream>>>(xb, wqkvb, Qb, Kbuf, Vtb,
                                                nullptr, 4096, 3072, 1024, 32);
  // Flash attention: qt descending (longest first), bh fastest-varying
  attn_fwd<<<dim3(32 * 32), 256, 0, stream>>>(Qb, Kbuf, Vtb, O2);
  // Output projection: M=4096, N=1024, K=1024 -> f32 out
  gemm_nt<0><<<dim3(32 * 8), 256, 0, stream>>>(O2, woutb, nullptr, nullptr,
                                               nullptr, out, 4096, 1024, 1024, 32);
}

// Round 8
// 199.132 us; speedup vs baseline: 1.3715x; 1.0328x over previous
//
#include <hip/hip_runtime.h>
#include <hip/hip_bf16.h>

// Attention block: x[2,2048,1024] @ w_qkv^T -> split heads (H=16, Hd=64) ->
// causal softmax attention -> @ w_out^T.
// Device dtypes: inputs FLOAT32, output FLOAT32. Internally bf16 MFMA + f32 acc.
// Pipeline: cvt_all (f32->bf16, fused) -> gemm_nt<1> (QKV proj; Q,K to
// [bh,L,64], V TRANSPOSED to [bh,64,L]) -> attn_fwd (flash, double-buffered
// K/Vt staging, peeled causal diagonal, 40KB LDS = 4 blocks/CU, deferred
// rescale, exp2-folded scale) -> gemm_nt<0> (out proj -> f32 d_out).

typedef __bf16 bf16;
typedef __bf16 bf16x8 __attribute__((ext_vector_type(8)));
typedef __bf16 bf16x4 __attribute__((ext_vector_type(4)));
typedef float  f32x4  __attribute__((ext_vector_type(4)));

#define MFMA16(a, b, c) __builtin_amdgcn_mfma_f32_16x16x32_bf16(a, b, c, 0, 0, 0)

// Fused f32->bf16 convert. Destinations are contiguous in d_ws:
// xb (1048576 float4) | wqkvb (786432) | woutb (262144).
__global__ __launch_bounds__(256) void cvt_all(
    const float* __restrict__ x, const float* __restrict__ wq,
    const float* __restrict__ wo, bf16* __restrict__ dst) {
  int i = blockIdx.x * 256 + threadIdx.x;  // float4 index, grid covers exactly
  const float* src;
  int off;
  if (i < 1048576) {
    src = x; off = i;
  } else if (i < 1048576 + 786432) {
    src = wq; off = i - 1048576;
  } else {
    src = wo; off = i - (1048576 + 786432);
  }
  float4 v = ((const float4*)src)[off];
  bf16x4 o;
  o[0] = (bf16)v.x; o[1] = (bf16)v.y; o[2] = (bf16)v.z; o[3] = (bf16)v.w;
  ((bf16x4*)dst)[i] = o;
}

__device__ __forceinline__ void gload_lds16(const bf16* g, bf16* l) {
  __builtin_amdgcn_global_load_lds(
      (const __attribute__((address_space(1))) void*)g,
      (__attribute__((address_space(3))) void*)l, 16, 0, 0);
}

// Stage a ROWS x 64 bf16 tile (row stride `ld` elems in global) into LDS.
// LDS layout is linear [ROWS][64] but each row's eight 16B slots are permuted
// by slot ^= (row&7)  (applied on the GLOBAL source side, since
// global_load_lds writes linearly: base + lane*16). Read back with read_swz.
template <int ROWS>
__device__ __forceinline__ void stage_tile(const bf16* __restrict__ src, int ld,
                                           bf16* lds, int tid) {
  const int wid = tid >> 6;
#pragma unroll
  for (int i = 0; i < ROWS / 32; ++i) {
    int c = i * 256 + tid;              // 16B chunk index
    int row = c >> 3;
    int slot = (c & 7) ^ (row & 7);     // pre-swizzled source slot
    gload_lds16(src + row * ld + slot * 8, lds + i * 2048 + wid * 512);
  }
}

// Read 8 contiguous bf16 of tile[row][kbyte/2 ..] with the XOR un-swizzle.
__device__ __forceinline__ bf16x8 read_swz(const bf16* lds, int row, int kbyte) {
  int byte = row * 128 + (kbyte ^ ((row & 7) << 4));
  return *(const bf16x8*)((const char*)lds + byte);
}

// C[m,n] = sum_k A[m,k] * Bt[n,k].  128x128 tile, BK=64, 4 waves in 2x2,
// each wave 64x64 (4x4 fragments of 16x16), mfma_f32_16x16x32_bf16.
// MODE 0: Cf row-major [M,N] FLOAT32.
// MODE 1: QKV scatter: Q,K -> C0/C1 [bh,2048,64] bf16; V -> C2 TRANSPOSED
//         [bh,64,2048] bf16 (so attention stages V^T directly).
template <int MODE>
__global__ __launch_bounds__(256) void gemm_nt(
    const bf16* __restrict__ A, const bf16* __restrict__ Bt,
    bf16* __restrict__ C0, bf16* __restrict__ C1, bf16* __restrict__ C2,
    float* __restrict__ Cf,
    int M, int N, int K, int nbm) {
  __shared__ bf16 ldsA[128 * 64];
  __shared__ bf16 ldsB[128 * 64];
  const int tid = threadIdx.x;
  const int lane = tid & 63, wid = tid >> 6;
  const int wr = wid >> 1, wc = wid & 1;
  const int bm = blockIdx.x % nbm, bn = blockIdx.x / nbm;
  const int l15 = lane & 15, g = lane >> 4;

  f32x4 acc[4][4] = {};
  const bf16* Ab = A + (size_t)bm * 128 * K;
  const bf16* Bb = Bt + (size_t)bn * 128 * K;

  for (int k0 = 0; k0 < K; k0 += 64) {
    __syncthreads();  // protect LDS from previous iteration's readers
    stage_tile<128>(Ab + k0, K, ldsA, tid);
    stage_tile<128>(Bb + k0, K, ldsB, tid);
    __syncthreads();  // drains vmcnt (compiler emits full waitcnt before barrier)
#pragma unroll
    for (int kc = 0; kc < 2; ++kc) {
      bf16x8 af[4], bfr[4];
#pragma unroll
      for (int mi = 0; mi < 4; ++mi)
        af[mi] = read_swz(ldsA, wr * 64 + mi * 16 + l15, kc * 64 + g * 16);
#pragma unroll
      for (int ni = 0; ni < 4; ++ni)
        bfr[ni] = read_swz(ldsB, wc * 64 + ni * 16 + l15, kc * 64 + g * 16);
#pragma unroll
      for (int mi = 0; mi < 4; ++mi)
#pragma unroll
        for (int ni = 0; ni < 4; ++ni)
          acc[mi][ni] = MFMA16(af[mi], bfr[ni], acc[mi][ni]);
    }
  }

  const int mbase = bm * 128 + wr * 64, nbase = bn * 128 + wc * 64;
#pragma unroll
  for (int mi = 0; mi < 4; ++mi) {
#pragma unroll
    for (int ni = 0; ni < 4; ++ni) {
#pragma unroll
      for (int r = 0; r < 4; ++r) {
        // D layout (m89-verified): col = lane&15, row = (lane>>4)*4 + r
        int m = mbase + mi * 16 + g * 4 + r;
        int n = nbase + ni * 16 + l15;
        if (MODE == 0) {
          Cf[(size_t)m * N + n] = acc[mi][ni][r];   // f32 output
        } else {
          bf16 v = (bf16)acc[mi][ni][r];
          int part = n >> 10;               // 0:Q 1:K 2:V
          int hh = (n >> 6) & 15, hd = n & 63;
          int bb = m >> 11, ll = m & 2047;
          size_t bhb = (size_t)(bb * 16 + hh);
          if (part == 2) {
            C2[(bhb * 64 + hd) * 2048 + ll] = v;          // V^T [bh][d][L]
          } else {
            bf16* dst = (part == 0) ? C0 : C1;
            dst[(bhb * 2048 + ll) * 64 + hd] = v;         // [bh][L][d]
          }
        }
      }
    }
  }
}

// Causal flash attention. Q/K: [bh, 2048, 64] bf16; Vt: [bh, 64, 2048] bf16.
// O2: [B*L, 1024] bf16 (head dim h*64+d within row -> out-proj is plain NT).
// Block: 256 threads = 4 waves; each wave owns 16 q-rows of a 64-row q-tile.
// Swapped QK^T: S^T = mfma(K_frag, Q_frag) so lane (q = lane&15) holds P
// values for its own q-row -> softmax is per-lane + shfl_xor(16,32).
// Double-buffered K/Vt staging; peeled causal diagonal; LDS exactly 40KB
// (XOR-swizzled P, no pad) -> 4 blocks/CU; deferred rescale (T13, THR=0);
// scale folded into exp2 constant; per-lane l partials reduced once at end.
__global__ __launch_bounds__(256) void attn_fwd(
    const bf16* __restrict__ Q, const bf16* __restrict__ Kb,
    const bf16* __restrict__ Vt, bf16* __restrict__ O2) {
  __shared__ bf16 ldsK[2][64 * 64];    // swizzled K tiles [64 kv][64 d]
  __shared__ bf16 ldsVt[2][64 * 64];   // swizzled V^T tiles [64 d][64 kv]
  __shared__ bf16 ldsP[4][16 * 64];    // per-wave P [16 q][64 kv], XOR-swizzled

  const int tid = threadIdx.x, lane = tid & 63, wid = tid >> 6;
  const int l15 = lane & 15, g = lane >> 4;
  const int qt = 31 - (blockIdx.x >> 5);  // longest blocks dispatched first
  const int bh = blockIdx.x & 31;
  const int b = bh >> 4, h = bh & 15;
  const bf16* Qh  = Q  + (size_t)bh * 2048 * 64;
  const bf16* Kh  = Kb + (size_t)bh * 2048 * 64;
  const bf16* VtH = Vt + (size_t)bh * 64 * 2048;
  const int q0 = qt * 64;
  const int qrow = q0 + wid * 16 + l15;  // this lane's q row

  // exp(s*0.125) == exp2(s * CE)
  const float CE = 0.18033688011112042f;

  // Q fragment (B operand): lane holds Q[qrow][dk*32 + g*8 + j], direct global.
  bf16x8 qf[2];
#pragma unroll
  for (int dk = 0; dk < 2; ++dk)
    qf[dk] = *(const bf16x8*)(Qh + (size_t)qrow * 64 + dk * 32 + g * 8);

  float m_run = -__builtin_inff();
  float l_lane = 0.f;                  // per-lane partial of softmax denom
  f32x4 oacc[4] = {};  // O^T[d = dsub*16 + g*4 + r][q = l15]

  // One K/V tile step. masked==true only for the diagonal tile (t == qt).
  auto step = [&](bool masked, int curb) {
    // S^T: A = K[16kv,32d], B = Q -> D[kvloc = g*4+r][q = l15]  (raw logits)
    f32x4 s[4] = {};
#pragma unroll
    for (int sub = 0; sub < 4; ++sub) {
#pragma unroll
      for (int dk = 0; dk < 2; ++dk) {
        bf16x8 kf = read_swz(&ldsK[curb][0], sub * 16 + l15, dk * 64 + g * 16);
        s[sub] = MFMA16(kf, qf[dk], s[sub]);
      }
    }
    if (masked) {
#pragma unroll
      for (int sub = 0; sub < 4; ++sub)
#pragma unroll
        for (int r = 0; r < 4; ++r) {
          int kvl = sub * 16 + g * 4 + r;          // kv local to tile
          if (kvl > wid * 16 + l15) s[sub][r] = -__builtin_inff();
        }
    }
    // balanced max tree over this lane's 16 raw logits
    float m0 = fmaxf(fmaxf(s[0][0], s[0][1]), fmaxf(s[0][2], s[0][3]));
    float m1 = fmaxf(fmaxf(s[1][0], s[1][1]), fmaxf(s[1][2], s[1][3]));
    float m2 = fmaxf(fmaxf(s[2][0], s[2][1]), fmaxf(s[2][2], s[2][3]));
    float m3 = fmaxf(fmaxf(s[3][0], s[3][1]), fmaxf(s[3][2], s[3][3]));
    float mt = fmaxf(fmaxf(m0, m1), fmaxf(m2, m3));
    mt = fmaxf(mt, __shfl_xor(mt, 16));
    mt = fmaxf(mt, __shfl_xor(mt, 32));            // uniform across q-row's 4 g-lanes
    // deferred rescale: only when the tile max exceeds the running max
    if (!__all(mt <= m_run)) {
      float mnew = fmaxf(m_run, mt);
      float alpha = exp2f((m_run - mnew) * CE);    // first tile: exp2(-inf)=0
#pragma unroll
      for (int dsub = 0; dsub < 4; ++dsub) {
        oacc[dsub][0] *= alpha; oacc[dsub][1] *= alpha;
        oacc[dsub][2] *= alpha; oacc[dsub][3] *= alpha;
      }
      l_lane *= alpha;
      m_run = mnew;
    }
    float lsum = 0.f;
#pragma unroll
    for (int sub = 0; sub < 4; ++sub) {
      bf16x4 pb;
#pragma unroll
      for (int r = 0; r < 4; ++r) {
        float e = exp2f((s[sub][r] - m_run) * CE);  // <= 1, masked -> 0
        lsum += e;
        pb[r] = (bf16)e;
      }
      int kbyte = sub * 32 + g * 8;                 // byte offset in 128B row
      *(bf16x4*)((char*)&ldsP[wid][0] +
                 (l15 * 128 + (kbyte ^ ((l15 & 7) << 4)))) = pb;
    }
    l_lane += lsum;
    // PV: O^T += V^T * P^T  (A = Vt frag rows=d, B = P^T frag, both swizzled)
#pragma unroll
    for (int kc = 0; kc < 2; ++kc) {
      bf16x8 pf = read_swz(&ldsP[wid][0], l15, kc * 64 + g * 16);
#pragma unroll
      for (int dsub = 0; dsub < 4; ++dsub) {
        bf16x8 vf = read_swz(&ldsVt[curb][0], dsub * 16 + l15, kc * 64 + g * 16);
        oacc[dsub] = MFMA16(vf, pf, oacc[dsub]);
      }
    }
  };

  // prologue: stage tile 0
  stage_tile<64>(Kh, 64, &ldsK[0][0], tid);
  stage_tile<64>(VtH, 2048, &ldsVt[0][0], tid);
  __syncthreads();

  int cur = 0;
  for (int t = 0; t < qt; ++t) {       // unmasked steps (kv tile strictly below diag)
    // prefetch tile t+1 into the other buffer (in flight during compute)
    stage_tile<64>(Kh + (size_t)(t + 1) * 64 * 64, 64, &ldsK[cur ^ 1][0], tid);
    stage_tile<64>(VtH + (t + 1) * 64, 2048, &ldsVt[cur ^ 1][0], tid);
    step(false, cur);
    __syncthreads();                   // staging drained + all waves done reading
    cur ^= 1;
  }
  step(true, cur);                     // diagonal tile, causal-masked

  float l_run = l_lane;
  l_run += __shfl_xor(l_run, 16);
  l_run += __shfl_xor(l_run, 32);
  const float linv = 1.f / l_run;
#pragma unroll
  for (int dsub = 0; dsub < 4; ++dsub)
#pragma unroll
    for (int r = 0; r < 4; ++r) {
      int d = dsub * 16 + g * 4 + r;
      O2[((size_t)(b * 2048 + qrow)) * 1024 + h * 64 + d] =
          (bf16)(oacc[dsub][r] * linv);
    }
}

extern "C" void kernel_launch(void* const* d_in, const int* in_sizes, int n_in,
                              void* d_out, int out_size, void* d_ws, size_t ws_size,
                              hipStream_t stream) {
  const float* x     = (const float*)d_in[0];   // [2,2048,1024] f32
  // d_in[1] = causal mask: known tril, not read
  const float* w_qkv = (const float*)d_in[2];   // [3072,1024] f32
  const float* w_out = (const float*)d_in[3];   // [1024,1024] f32
  float* out = (float*)d_out;                   // [2,2048,1024] f32

  char* ws = (char*)d_ws;
  bf16* xb    = (bf16*)(ws);                        // [4096,1024]   8 MiB
  bf16* wqkvb = (bf16*)(ws + ((size_t)8 << 20));    // [3072,1024]   6 MiB
  bf16* woutb = (bf16*)(ws + ((size_t)14 << 20));   // [1024,1024]   2 MiB
  bf16* Qb    = (bf16*)(ws + ((size_t)16 << 20));   // [32,2048,64]  8 MiB
  bf16* Kbuf  = (bf16*)(ws + ((size_t)24 << 20));   // [32,2048,64]  8 MiB
  bf16* Vtb   = (bf16*)(ws + ((size_t)32 << 20));   // [32,64,2048]  8 MiB (V^T)
  bf16* O2    = (bf16*)(ws + ((size_t)40 << 20));   // [4096,1024]   8 MiB

  // fused f32 -> bf16 conversion (dst regions contiguous at ws base)
  cvt_all<<<dim3(8192), 256, 0, stream>>>(x, w_qkv, w_out, xb);

  // QKV projection: M=4096, N=3072, K=1024 (V stored transposed)
  gemm_nt<1><<<dim3(32 * 24), 256, 0, stream>>>(xb, wqkvb, Qb, Kbuf, Vtb,
                                                nullptr, 4096, 3072, 1024, 32);
  // Flash attention: qt descending (longest first), bh fastest-varying
  attn_fwd<<<dim3(32 * 32), 256, 0, stream>>>(Qb, Kbuf, Vtb, O2);
  // Output projection: M=4096, N=1024, K=1024 -> f32 out
  gemm_nt<0><<<dim3(32 * 8), 256, 0, stream>>>(O2, woutb, nullptr, nullptr,
                                               nullptr, out, 4096, 1024, 1024, 32);
}